// Round 1
// baseline (510.871 us; speedup 1.0000x reference)
//
#include <hip/hip_runtime.h>

// ---------------- problem constants ----------------
#define NG   64            // graphs
#define NPG  4096          // nodes per graph
#define C    256           // channels
#define NTOT (NG * NPG)    // 262144 nodes
#define K    2048          // kept per graph (ceil(0.5*4096))
#define KT   (NG * K)      // 131072 kept total
#define EPG  (NPG * 16)    // 65536 edges per graph
#define ET   (NG * EPG)    // 4194304 edges total

// output layout (floats), concatenated in reference return order
#define OFF_X     0
#define OFF_EI    (KT * C)                 // 33554432
#define OFF_ATTR  (OFF_EI + 2 * ET)        // 41943040
#define OFF_BATCH (OFF_ATTR + ET)          // 46137344
#define OFF_PERM  (OFF_BATCH + KT)         // 46268416
#define OFF_SCORE (OFF_PERM + KT)          // 46399488
#define OFF_MASK  (OFF_SCORE + KT)         // 46530560
// total = 50724864

// XLA/Eigen FastTanh for f32 — bitwise-matches XLA's EmitTanh(F32):
// |x| < 0.0004 -> x; clamp to +/-7.90531110763549805; odd/even rational poly.
__device__ __forceinline__ float xla_tanh(float x) {
  float ax = fabsf(x);
  if (ax < 0.0004f) return x;
  const float c = 7.90531110763549805f;
  float t = fminf(fmaxf(x, -c), c);
  float x2 = t * t;
  float p = fmaf(x2, -2.76076847742355e-16f, 2.00018790482477e-13f);
  p = fmaf(x2, p, -8.60467152213735e-11f);
  p = fmaf(x2, p, 5.12229709037114e-08f);
  p = fmaf(x2, p, 1.48572235717979e-05f);
  p = fmaf(x2, p, 6.37261928875436e-04f);
  p = fmaf(x2, p, 4.89352455891786e-03f);
  p = t * p;
  float q = fmaf(x2, 1.19825839466702e-06f, 1.18534705686654e-04f);
  q = fmaf(x2, q, 2.26843463243900e-03f);
  q = fmaf(x2, q, 4.89352518554385e-03f);
  return p / q;
}

// ---------------- kernel 1: scores ----------------
// one wave (64 lanes) per node; lane loads float4 of x-row and of w.
__global__ __launch_bounds__(256) void score_kernel(
    const float* __restrict__ x, const float* __restrict__ w,
    float* __restrict__ scores) {
  int node = (int)((blockIdx.x * blockDim.x + threadIdx.x) >> 6);
  int lane = threadIdx.x & 63;
  if (node >= NTOT) return;
  const float4 xv = *reinterpret_cast<const float4*>(x + (size_t)node * C + lane * 4);
  const float4 wv = *reinterpret_cast<const float4*>(w + lane * 4);
  float d = xv.x * wv.x;
  d = fmaf(xv.y, wv.y, d);
  d = fmaf(xv.z, wv.z, d);
  d = fmaf(xv.w, wv.w, d);
  float n = wv.x * wv.x;
  n = fmaf(wv.y, wv.y, n);
  n = fmaf(wv.z, wv.z, n);
  n = fmaf(wv.w, wv.w, n);
  #pragma unroll
  for (int off = 1; off < 64; off <<= 1) {
    d += __shfl_xor(d, off);
    n += __shfl_xor(n, off);
  }
  if (lane == 0) scores[node] = xla_tanh(d / sqrtf(n));
}

// ---------------- kernel 2: per-graph bitonic top-k ----------------
// key = (~orderable(score) << 32) | idx  -> ascending u64 sort gives
// score descending, index ascending on ties (matches jax.lax.top_k).
__global__ __launch_bounds__(1024) void topk_kernel(
    const float* __restrict__ scores, int* __restrict__ perm_i32,
    int* __restrict__ new_id, float* __restrict__ out) {
  __shared__ unsigned long long keys[NPG];
  const int g = blockIdx.x;
  const int t = threadIdx.x;
  const float* s = scores + g * NPG;

  for (int i = t; i < NPG; i += 1024) {
    unsigned int u = __float_as_uint(s[i]);
    u = (u & 0x80000000u) ? ~u : (u | 0x80000000u);  // ascending-orderable
    u = ~u;                                          // descending
    keys[i] = ((unsigned long long)u << 32) | (unsigned int)i;
  }

  for (int k = 2; k <= NPG; k <<= 1) {
    for (int j = k >> 1; j > 0; j >>= 1) {
      __syncthreads();
      #pragma unroll
      for (int q = 0; q < 2; ++q) {
        int p = t + q * 1024;
        int i = ((p & ~(j - 1)) << 1) | (p & (j - 1));
        int l = i | j;
        unsigned long long a = keys[i], b = keys[l];
        bool up = ((i & k) == 0);
        if ((a > b) == up) { keys[i] = b; keys[l] = a; }
      }
    }
  }
  __syncthreads();

  for (int r = t; r < NPG; r += 1024) {
    int idx = (int)(keys[r] & 0xFFFFFFFFu);
    int node = g * NPG + idx;
    if (r < K) {
      int nid = g * K + r;
      new_id[node] = nid;
      perm_i32[nid] = node;
      out[OFF_BATCH + nid] = (float)g;
      out[OFF_PERM + nid]  = (float)node;
      out[OFF_SCORE + nid] = s[idx];
    } else {
      new_id[node] = -1;
    }
  }
}

// ---------------- kernel 3: gather x_out = x[perm] ----------------
__global__ __launch_bounds__(256) void gather_kernel(
    const float* __restrict__ x, const int* __restrict__ perm_i32,
    float* __restrict__ out) {
  int row = (int)((blockIdx.x * blockDim.x + threadIdx.x) >> 6);
  int lane = threadIdx.x & 63;
  if (row >= KT) return;
  int node = perm_i32[row];
  *reinterpret_cast<float4*>(out + OFF_X + (size_t)row * C + lane * 4) =
      *reinterpret_cast<const float4*>(x + (size_t)node * C + lane * 4);
}

// ---------------- kernel 4: edge filter, 4 edges/thread ----------------
__global__ __launch_bounds__(256) void edge_kernel(
    const int* __restrict__ ei, const float* __restrict__ attr,
    const int* __restrict__ new_id, float* __restrict__ out) {
  int t = blockIdx.x * blockDim.x + threadIdx.x;
  if (t >= ET / 4) return;
  int4 r = reinterpret_cast<const int4*>(ei)[t];
  int4 c = reinterpret_cast<const int4*>(ei + ET)[t];
  float4 a = reinterpret_cast<const float4*>(attr)[t];

  int nr[4] = {new_id[r.x], new_id[r.y], new_id[r.z], new_id[r.w]};
  int nc[4] = {new_id[c.x], new_id[c.y], new_id[c.z], new_id[c.w]};
  float4 e0, e1, ao, mo;
  float* e0p = &e0.x; float* e1p = &e1.x; float* aop = &ao.x; float* mop = &mo.x;
  const float* ap = &a.x;
  #pragma unroll
  for (int i = 0; i < 4; ++i) {
    bool keep = (nr[i] >= 0) && (nc[i] >= 0);
    e0p[i] = keep ? (float)nr[i] : -1.0f;
    e1p[i] = keep ? (float)nc[i] : -1.0f;
    aop[i] = keep ? ap[i] : 0.0f;
    mop[i] = keep ? 1.0f : 0.0f;
  }
  reinterpret_cast<float4*>(out + OFF_EI)[t]        = e0;
  reinterpret_cast<float4*>(out + OFF_EI + ET)[t]   = e1;
  reinterpret_cast<float4*>(out + OFF_ATTR)[t]      = ao;
  reinterpret_cast<float4*>(out + OFF_MASK)[t]      = mo;
}

// ---------------- launch ----------------
extern "C" void kernel_launch(void* const* d_in, const int* in_sizes, int n_in,
                              void* d_out, int out_size, void* d_ws, size_t ws_size,
                              hipStream_t stream) {
  const float* x    = (const float*)d_in[0];
  const int*   ei   = (const int*)d_in[1];
  const float* attr = (const float*)d_in[2];
  // d_in[3] = batch (unused; derivable)
  const float* w    = (const float*)d_in[4];
  float* out = (float*)d_out;

  float* scores   = (float*)d_ws;                 // NTOT floats
  int*   perm_i32 = (int*)d_ws + NTOT;            // KT ints
  int*   new_id   = (int*)d_ws + NTOT + KT;       // NTOT ints

  score_kernel<<<dim3(NTOT * 64 / 256), dim3(256), 0, stream>>>(x, w, scores);
  topk_kernel<<<dim3(NG), dim3(1024), 0, stream>>>(scores, perm_i32, new_id, out);
  gather_kernel<<<dim3(KT * 64 / 256), dim3(256), 0, stream>>>(x, perm_i32, out);
  edge_kernel<<<dim3(ET / 4 / 256), dim3(256), 0, stream>>>(ei, attr, new_id, out);
}